// Round 2
// baseline (12477.843 us; speedup 1.0000x reference)
//
#include <hip/hip_runtime.h>
#include <hip/hip_bf16.h>

typedef _Float16 f16;
typedef _Float16 f16x8 __attribute__((ext_vector_type(8)));
typedef _Float16 f16x4 __attribute__((ext_vector_type(4)));
typedef float f32x4 __attribute__((ext_vector_type(4)));

#define SN 2048
#define IN_ 128
#define TCH 32
#define WUP 96
#define RR 32
#define HPAD 280

#define WB0_SZ (384 * 1024)
#define WB1_SZ (512 * 1024)
#define WBO_SZ (256 * 128)
#define BIAS_OFF_B ((WB0_SZ + WB1_SZ + WBO_SZ) * 2)

struct PrepArgs {
  const float* W[8];   // ff1_0, ff2_0, ta_0, tb_0, ff1_1, ff2_1, ta_1, tb_1
  const float* b[8];
  const float* Wout;
  const float* bout;
};

// Pack f32 weights into per-(frag,lane) f16x8 groups.
// k-map (identical for A and B fragments -> permutation-safe):
//   element e of lane l in k-tile kt covers k = kt*32 + (l>>4)*8 + e
//   col n = nt*16 + (l&15)
__global__ void prep_kernel(PrepArgs p, f16* wbase, float* bbase) {
  int g = blockIdx.x * blockDim.x + threadIdx.x;
  const int NF0 = 12 * 64;
  const int NF1 = 16 * 64;
  const int NFO = 8 * 8;
  const int E0 = NF0 * 64, E1 = E0 + NF1 * 64, E2 = E1 + NFO * 64;
  if (g < E0) {
    int f = g >> 6, lane = g & 63;
    int kt = f >> 6, nt = f & 63;
    int k = kt * 32 + ((lane >> 4) << 3);
    int n = nt * 16 + (lane & 15);
    const float* W = p.W[n >> 8];    // layer0 weight [384][256]
    int j = n & 255;
    f16x8 v;
#pragma unroll
    for (int e = 0; e < 8; ++e) v[e] = (f16)W[(k + e) * 256 + j];
    *(f16x8*)(wbase + (size_t)g * 8) = v;
  } else if (g < E1) {
    int g1 = g - E0;
    int f = g1 >> 6, lane = g1 & 63;
    int kt = f >> 6, nt = f & 63;
    int k = kt * 32 + ((lane >> 4) << 3);
    int n = nt * 16 + (lane & 15);
    const float* W = p.W[4 + (n >> 8)];  // layer1 weight [512][256]
    int j = n & 255;
    f16x8 v;
#pragma unroll
    for (int e = 0; e < 8; ++e) v[e] = (f16)W[(k + e) * 256 + j];
    *(f16x8*)(wbase + (size_t)WB0_SZ + (size_t)g1 * 8) = v;
  } else if (g < E2) {
    int g2 = g - E1;
    int f = g2 >> 6, lane = g2 & 63;
    int kt = f >> 3, nt = f & 7;
    int k = kt * 32 + ((lane >> 4) << 3);
    int n = nt * 16 + (lane & 15);
    f16x8 v;
#pragma unroll
    for (int e = 0; e < 8; ++e) v[e] = (f16)p.Wout[(k + e) * 128 + n];
    *(f16x8*)(wbase + (size_t)(WB0_SZ + WB1_SZ) + (size_t)g2 * 8) = v;
  } else {
    int g3 = g - E2;
    if (g3 < 1024) {
      bbase[g3] = p.b[g3 >> 8][g3 & 255];
    } else if (g3 < 2048) {
      int q = g3 - 1024;
      bbase[1024 + q] = p.b[4 + (q >> 8)][q & 255];
    } else if (g3 < 2176) {
      bbase[2048 + (g3 - 2048)] = p.bout[g3 - 2048];
    }
  }
}

__device__ __forceinline__ float fast_tanh(float v) {
  float e = __expf(2.f * v);
  return 1.f - 2.f / (e + 1.f);
}
__device__ __forceinline__ float fast_sigmoid(float v) {
  return 1.f / (1.f + __expf(-v));
}

#define MFMA16(a, b, c) __builtin_amdgcn_mfma_f32_16x16x32_f16((a), (b), (c), 0, 0, 0)

// 256 blocks = 64 time-chunks (TCH=32, WUP=96) x 4 row-groups of 32 rows.
// 16 waves/block (4 per SIMD). Wave w owns h-cols [16w,16w+16): gate n-tiles
// {g*16+w} for g=0..3 -> all four gates of a given (row,col) sit in the SAME
// lane -> elementwise fully in registers.
// Per-wave kt-loops use an explicit 2-deep register double-buffer of the 4
// B-fragments so >=4 global loads are always in flight per wave.
__global__ __launch_bounds__(1024, 4)
void scan_kernel(const float* __restrict__ x, const float* __restrict__ dtp,
                 const f16* __restrict__ wb0, const f16* __restrict__ wb1,
                 const f16* __restrict__ wbO, const float* __restrict__ bb,
                 float* __restrict__ out) {   // *** d_out is FLOAT32 ***
  __shared__ __align__(16) f16 xA[RR][136];
  __shared__ __align__(16) f16 h0s[2][RR][HPAD];   // double-buffered states
  __shared__ __align__(16) f16 h1s[2][RR][HPAD];
  __shared__ float bs0[1024];
  __shared__ float bs1[1024];
  __shared__ float bsO[128];
  __shared__ float dts[2][RR];

  const int tid = threadIdx.x;
  const int lane = tid & 63;
  const int w = tid >> 6;                 // 0..15
  const int c = blockIdx.x >> 2;          // time chunk 0..63
  const int r0 = (blockIdx.x & 3) * RR;   // batch-row base

  bs0[tid & 1023] = bb[tid & 1023];
  bs1[tid & 1023] = bb[1024 + (tid & 1023)];
  if (tid < 128) bsO[tid] = bb[2048 + tid];
  for (int i = tid; i < 2 * RR * HPAD; i += 1024) {
    (&h0s[0][0][0])[i] = (f16)0.f;
    (&h1s[0][0][0])[i] = (f16)0.f;
  }

  int tb = c * TCH - WUP;
  if (tb < 0) tb = 0;
  const int te = (c + 1) * TCH;
  const int tw = c * TCH;

  const int mrow = lane & 15;
  const int kgrp = (lane >> 4) * 8;
  const int rbase = (lane >> 4) * 4;

  // weight base pointers for this wave's n-tiles (frag (kt,g) at +(kt*64+g*16)*64)
  const f16x8* wp0 = (const f16x8*)wb0 + (size_t)w * 64 + lane;
  const f16x8* wp1 = (const f16x8*)wb1 + (size_t)w * 64 + lane;
  const f16x8* wpO = (const f16x8*)wbO + (size_t)(w & 7) * 64 + lane;

  // x/dt: thread covers 4 cols of one row
  const int xi = tid >> 5;          // 0..31
  const int xk = (tid & 31) * 4;    // 0..124
  float4 xr = *(const float4*)(x + ((size_t)(r0 + xi) * SN + tb) * IN_ + xk);
  float dtr = (tid < RR) ? dtp[(size_t)(r0 + tid) * SN + tb] : 0.f;

  { f16x4 xv = { (f16)xr.x, (f16)xr.y, (f16)xr.z, (f16)xr.w };
    *(f16x4*)&xA[xi][xk] = xv; }
  if (tid < RR) dts[0][tid] = dtr;
  __syncthreads();                 // h zeroed, biases, xA(tb), dts visible
  xr = *(const float4*)(x + ((size_t)(r0 + xi) * SN + (tb + 1)) * IN_ + xk);
  if (tid < RR) dtr = dtp[(size_t)(r0 + tid) * SN + (tb + 1)];

  int rp = 0, dp = 0;
  for (int t = tb; t < te; ++t) {
    const int wpb = rp ^ 1;

    // ---- phase A: layer 0 gates [32 x 1024] = [x(t) | h0_old] @ W0cat ----
    {
      f32x4 acc[4][2];   // [gate][mtile]
#pragma unroll
      for (int g = 0; g < 4; ++g) {
        float bv = bs0[(g * 16 + w) * 16 + mrow];
        acc[g][0] = (f32x4){bv, bv, bv, bv};
        acc[g][1] = (f32x4){bv, bv, bv, bv};
      }
      f16x8 bA0 = wp0[0], bA1 = wp0[16 * 64], bA2 = wp0[32 * 64], bA3 = wp0[48 * 64];
#pragma unroll
      for (int kt = 0; kt < 12; ++kt) {
        f16x8 bB0 = bA0, bB1 = bA1, bB2 = bA2, bB3 = bA3;
        if (kt < 11) {
          size_t o = (size_t)(kt + 1) * 64 * 64;
          bB0 = wp0[o]; bB1 = wp0[o + 16 * 64];
          bB2 = wp0[o + 32 * 64]; bB3 = wp0[o + 48 * 64];
        }
        f16x8 a0, a1;
        if (kt < 4) {
          a0 = *(const f16x8*)&xA[mrow][kt * 32 + kgrp];
          a1 = *(const f16x8*)&xA[16 + mrow][kt * 32 + kgrp];
        } else {
          a0 = *(const f16x8*)&h0s[rp][mrow][(kt - 4) * 32 + kgrp];
          a1 = *(const f16x8*)&h0s[rp][16 + mrow][(kt - 4) * 32 + kgrp];
        }
        acc[0][0] = MFMA16(a0, bA0, acc[0][0]); acc[0][1] = MFMA16(a1, bA0, acc[0][1]);
        acc[1][0] = MFMA16(a0, bA1, acc[1][0]); acc[1][1] = MFMA16(a1, bA1, acc[1][1]);
        acc[2][0] = MFMA16(a0, bA2, acc[2][0]); acc[2][1] = MFMA16(a1, bA2, acc[2][1]);
        acc[3][0] = MFMA16(a0, bA3, acc[3][0]); acc[3][1] = MFMA16(a1, bA3, acc[3][1]);
        bA0 = bB0; bA1 = bB1; bA2 = bB2; bA3 = bB3;
      }
      // elementwise in registers -> h0 new buffer
#pragma unroll
      for (int mt = 0; mt < 2; ++mt)
#pragma unroll
        for (int ri = 0; ri < 4; ++ri) {
          int row = mt * 16 + rbase + ri;
          float d = dts[dp][row];
          float f1 = fast_tanh(acc[0][mt][ri]);
          float f2 = fast_tanh(acc[1][mt][ri]);
          float sg = fast_sigmoid(acc[2][mt][ri] * d + acc[3][mt][ri]);
          h0s[wpb][row][w * 16 + mrow] = (f16)(f1 + sg * (f2 - f1));
        }
    }
    __syncthreads();                                  // B1: new h0 visible, xA free

    // ---- phase B: stage x(t+1), prefetch x(t+2), layer 1 gates ----
    { f16x4 xv = { (f16)xr.x, (f16)xr.y, (f16)xr.z, (f16)xr.w };
      *(f16x4*)&xA[xi][xk] = xv; }
    if (tid < RR) dts[dp ^ 1][tid] = dtr;
    if (t + 2 < te) {
      xr = *(const float4*)(x + ((size_t)(r0 + xi) * SN + (t + 2)) * IN_ + xk);
      if (tid < RR) dtr = dtp[(size_t)(r0 + tid) * SN + (t + 2)];
    }
    {
      f32x4 acc[4][2];
#pragma unroll
      for (int g = 0; g < 4; ++g) {
        float bv = bs1[(g * 16 + w) * 16 + mrow];
        acc[g][0] = (f32x4){bv, bv, bv, bv};
        acc[g][1] = (f32x4){bv, bv, bv, bv};
      }
      f16x8 bA0 = wp1[0], bA1 = wp1[16 * 64], bA2 = wp1[32 * 64], bA3 = wp1[48 * 64];
#pragma unroll
      for (int kt = 0; kt < 16; ++kt) {
        f16x8 bB0 = bA0, bB1 = bA1, bB2 = bA2, bB3 = bA3;
        if (kt < 15) {
          size_t o = (size_t)(kt + 1) * 64 * 64;
          bB0 = wp1[o]; bB1 = wp1[o + 16 * 64];
          bB2 = wp1[o + 32 * 64]; bB3 = wp1[o + 48 * 64];
        }
        f16x8 a0, a1;
        if (kt < 8) {
          a0 = *(const f16x8*)&h0s[wpb][mrow][kt * 32 + kgrp];
          a1 = *(const f16x8*)&h0s[wpb][16 + mrow][kt * 32 + kgrp];
        } else {
          a0 = *(const f16x8*)&h1s[rp][mrow][(kt - 8) * 32 + kgrp];
          a1 = *(const f16x8*)&h1s[rp][16 + mrow][(kt - 8) * 32 + kgrp];
        }
        acc[0][0] = MFMA16(a0, bA0, acc[0][0]); acc[0][1] = MFMA16(a1, bA0, acc[0][1]);
        acc[1][0] = MFMA16(a0, bA1, acc[1][0]); acc[1][1] = MFMA16(a1, bA1, acc[1][1]);
        acc[2][0] = MFMA16(a0, bA2, acc[2][0]); acc[2][1] = MFMA16(a1, bA2, acc[2][1]);
        acc[3][0] = MFMA16(a0, bA3, acc[3][0]); acc[3][1] = MFMA16(a1, bA3, acc[3][1]);
        bA0 = bB0; bA1 = bB1; bA2 = bB2; bA3 = bB3;
      }
#pragma unroll
      for (int mt = 0; mt < 2; ++mt)
#pragma unroll
        for (int ri = 0; ri < 4; ++ri) {
          int row = mt * 16 + rbase + ri;
          float d = dts[dp][row];
          float f1 = fast_tanh(acc[0][mt][ri]);
          float f2 = fast_tanh(acc[1][mt][ri]);
          float sg = fast_sigmoid(acc[2][mt][ri] * d + acc[3][mt][ri]);
          h1s[wpb][row][w * 16 + mrow] = (f16)(f1 + sg * (f2 - f1));
        }
    }
    __syncthreads();                                  // B2: new h1, xA(t+1) visible

    // ---- phase C: y = h1 @ Wout + bout (wave w: n-tile w&7, m-tile w>>3) ----
    if (t >= tw) {
      // transient weight loads (only the output iters pay for these)
      f16x8 w0 = wpO[0 * 8 * 64], w1 = wpO[1 * 8 * 64], w2 = wpO[2 * 8 * 64],
            w3 = wpO[3 * 8 * 64], w4 = wpO[4 * 8 * 64], w5 = wpO[5 * 8 * 64],
            w6 = wpO[6 * 8 * 64], w7 = wpO[7 * 8 * 64];
      const int mr = (w >> 3) * 16;
      float bv = bsO[(w & 7) * 16 + mrow];
      f32x4 ao = (f32x4){bv, bv, bv, bv};
      ao = MFMA16(*(const f16x8*)&h1s[wpb][mr + mrow][0 * 32 + kgrp], w0, ao);
      ao = MFMA16(*(const f16x8*)&h1s[wpb][mr + mrow][1 * 32 + kgrp], w1, ao);
      ao = MFMA16(*(const f16x8*)&h1s[wpb][mr + mrow][2 * 32 + kgrp], w2, ao);
      ao = MFMA16(*(const f16x8*)&h1s[wpb][mr + mrow][3 * 32 + kgrp], w3, ao);
      ao = MFMA16(*(const f16x8*)&h1s[wpb][mr + mrow][4 * 32 + kgrp], w4, ao);
      ao = MFMA16(*(const f16x8*)&h1s[wpb][mr + mrow][5 * 32 + kgrp], w5, ao);
      ao = MFMA16(*(const f16x8*)&h1s[wpb][mr + mrow][6 * 32 + kgrp], w6, ao);
      ao = MFMA16(*(const f16x8*)&h1s[wpb][mr + mrow][7 * 32 + kgrp], w7, ao);
#pragma unroll
      for (int ri = 0; ri < 4; ++ri)
        out[((size_t)(r0 + mr + rbase + ri) * SN + t) * 128 + (w & 7) * 16 + mrow] = ao[ri];
    }
    rp ^= 1; dp ^= 1;
    // phase C (reads h1s[wpb], global stores) overlaps only with next phase A
    // (reads xA/h0s, writes h0s[old rp]) -> disjoint LDS; B1/B2 order the rest.
  }
}

extern "C" void kernel_launch(void* const* d_in, const int* in_sizes, int n_in,
                              void* d_out, int out_size, void* d_ws, size_t ws_size,
                              hipStream_t stream) {
  PrepArgs p;
  for (int i = 0; i < 8; ++i) {
    p.W[i] = (const float*)d_in[2 + 2 * i];
    p.b[i] = (const float*)d_in[3 + 2 * i];
  }
  p.Wout = (const float*)d_in[18];
  p.bout = (const float*)d_in[19];
  const float* x  = (const float*)d_in[0];
  const float* dt = (const float*)d_in[1];

  f16* wbase = (f16*)d_ws;
  float* bbase = (float*)((char*)d_ws + BIAS_OFF_B);

  const int prep_threads = (12 * 64 + 16 * 64 + 8 * 8) * 64 + 2176;
  int prep_blocks = (prep_threads + 255) / 256;
  prep_kernel<<<prep_blocks, 256, 0, stream>>>(p, wbase, bbase);

  const f16* wb0 = wbase;
  const f16* wb1 = wbase + WB0_SZ;
  const f16* wbO = wbase + WB0_SZ + WB1_SZ;

  scan_kernel<<<256, 1024, 0, stream>>>(x, dt, wb0, wb1, wbO,
                                        (const float*)bbase, (float*)d_out);
}